// Round 19
// baseline (184.622 us; speedup 1.0000x reference)
//
#include <hip/hip_runtime.h>

#define BB 4
#define NN 256
#define DD 256
#define HH 256
#define NEGV -1.0e9f

typedef _Float16 half8 __attribute__((ext_vector_type(8)));
typedef __fp16   fp16x2 __attribute__((ext_vector_type(2)));
typedef float floatx4 __attribute__((ext_vector_type(4)));

// ---------------- wconv: Wc/Wd -> f16 fragment-contiguous (R13 map) ------------
// Wst layout: [ks 0..15][hgrp 0..15][q 0..3][cc 0..15][e 0..7] halves.
__global__ __launch_bounds__(256) void wconv_kernel(const float* __restrict__ W1,
                                                    _Float16* __restrict__ Wst) {
  const int g = blockIdx.x;    // d = 0..255
  const int h = threadIdx.x;   // 0..255
  const float wcv = W1[(size_t)(2 * DD + g) * HH + h];
  const float wdv = W1[(size_t)(3 * DD + g) * HH + h];
  const int ks = g >> 4;
  const int dd = g & 15;
  const int q  = dd >> 2;
  const int e  = (dd & 3) * 2;
  const int hgrp = h >> 4;
  const int ccw  = h & 15;
  _Float16* p = Wst + ((size_t)((ks * 16 + hgrp) * 4 + q) * 16 + ccw) * 8 + e;
  p[0] = (_Float16)wcv;
  p[1] = (_Float16)wdv;
}

// ---------------- prep_st: S/T projections, RPB=8 ------------------------------
// 128 blocks x 8 rows: W1 traffic 128 x 512 KB = 64 MB (4x less than R17's
// 2-row version — prep was the bulk of the 67us non-score time). Named scalar
// accumulators (no local arrays -> no PromoteAlloca, the R6 lesson).
__global__ __launch_bounds__(256) void prep_st(const float* __restrict__ X,
                                               const float* __restrict__ W1,
                                               float* __restrict__ S,
                                               float* __restrict__ T) {
  const int g = blockIdx.x;    // 0..127
  const int h = threadIdx.x;   // 0..255
  const int row0 = g * 8;
  __shared__ float xr[8][DD];
#pragma unroll
  for (int r = 0; r < 8; ++r) xr[r][h] = X[(size_t)(row0 + r) * DD + h];
  __syncthreads();

  const float* __restrict__ Wa = W1;
  const float* __restrict__ Wb = W1 + (size_t)DD * HH;
  float sa0 = 0.f, sa1 = 0.f, sa2 = 0.f, sa3 = 0.f;
  float sa4 = 0.f, sa5 = 0.f, sa6 = 0.f, sa7 = 0.f;
  float sb0 = 0.f, sb1 = 0.f, sb2 = 0.f, sb3 = 0.f;
  float sb4 = 0.f, sb5 = 0.f, sb6 = 0.f, sb7 = 0.f;
#pragma unroll 4
  for (int d = 0; d < DD; ++d) {
    const float wa = Wa[(size_t)d * HH + h];
    const float wb = Wb[(size_t)d * HH + h];
    sa0 = fmaf(xr[0][d], wa, sa0);  sb0 = fmaf(xr[0][d], wb, sb0);
    sa1 = fmaf(xr[1][d], wa, sa1);  sb1 = fmaf(xr[1][d], wb, sb1);
    sa2 = fmaf(xr[2][d], wa, sa2);  sb2 = fmaf(xr[2][d], wb, sb2);
    sa3 = fmaf(xr[3][d], wa, sa3);  sb3 = fmaf(xr[3][d], wb, sb3);
    sa4 = fmaf(xr[4][d], wa, sa4);  sb4 = fmaf(xr[4][d], wb, sb4);
    sa5 = fmaf(xr[5][d], wa, sa5);  sb5 = fmaf(xr[5][d], wb, sb5);
    sa6 = fmaf(xr[6][d], wa, sa6);  sb6 = fmaf(xr[6][d], wb, sb6);
    sa7 = fmaf(xr[7][d], wa, sa7);  sb7 = fmaf(xr[7][d], wb, sb7);
  }
  S[(size_t)(row0 + 0) * HH + h] = sa0;  T[(size_t)(row0 + 0) * HH + h] = sb0;
  S[(size_t)(row0 + 1) * HH + h] = sa1;  T[(size_t)(row0 + 1) * HH + h] = sb1;
  S[(size_t)(row0 + 2) * HH + h] = sa2;  T[(size_t)(row0 + 2) * HH + h] = sb2;
  S[(size_t)(row0 + 3) * HH + h] = sa3;  T[(size_t)(row0 + 3) * HH + h] = sb3;
  S[(size_t)(row0 + 4) * HH + h] = sa4;  T[(size_t)(row0 + 4) * HH + h] = sb4;
  S[(size_t)(row0 + 5) * HH + h] = sa5;  T[(size_t)(row0 + 5) * HH + h] = sb5;
  S[(size_t)(row0 + 6) * HH + h] = sa6;  T[(size_t)(row0 + 6) * HH + h] = sb6;
  S[(size_t)(row0 + 7) * HH + h] = sa7;  T[(size_t)(row0 + 7) * HH + h] = sb7;
}

__device__ __forceinline__ half8 make_afrag(const float4 xi, const float4 xj) {
  fp16x2 p0 = __builtin_amdgcn_cvt_pkrtz(__builtin_fabsf(xi.x - xj.x), xi.x * xj.x);
  fp16x2 p1 = __builtin_amdgcn_cvt_pkrtz(__builtin_fabsf(xi.y - xj.y), xi.y * xj.y);
  fp16x2 p2 = __builtin_amdgcn_cvt_pkrtz(__builtin_fabsf(xi.z - xj.z), xi.z * xj.z);
  fp16x2 p3 = __builtin_amdgcn_cvt_pkrtz(__builtin_fabsf(xi.w - xj.w), xi.w * xj.w);
  uint4 u;
  u.x = __builtin_bit_cast(unsigned int, p0);
  u.y = __builtin_bit_cast(unsigned int, p1);
  u.z = __builtin_bit_cast(unsigned int, p2);
  u.w = __builtin_bit_cast(unsigned int, p3);
  return __builtin_bit_cast(half8, u);
}

#define MFMA16(af, bf, acc) acc = __builtin_amdgcn_mfma_f32_16x16x32_f16(af, bf, acc, 0, 0, 0)

// ---------------- score: SYMMETRY-PRUNED pair tiles (R18, unchanged) -----------
__global__ __launch_bounds__(256, 2) void score_mfma(
    const float* __restrict__ X,  const float* __restrict__ b1,
    const float* __restrict__ W2, const float* __restrict__ b2,
    const float* __restrict__ S,  const float* __restrict__ T,
    const _Float16* __restrict__ Wst, float* __restrict__ Sc) {

  const int beta = blockIdx.x;      // 0..639
  const int b    = blockIdx.y;
  int i, qt;
  if (beta < 256)      { i = beta >> 2;                    qt = beta & 3; }
  else if (beta < 448) { const int g = beta - 256; const int d3 = g / 3;
                         i = 64 + d3;                      qt = 1 + (g - 3 * d3); }
  else if (beta < 576) { const int g = beta - 448;
                         i = 128 + (g >> 1);               qt = 2 + (g & 1); }
  else                 { i = 192 + (beta - 576);           qt = 3; }
  const int bi    = b * NN + i;
  const int jbase = qt * 64;
  const int isUp  = qt > (i >> 6);  // block-uniform

  const int t     = threadIdx.x;
  const int lane  = t & 63;
  const int hg    = t >> 6;         // 0..3
  const int q     = lane >> 4;
  const int cc    = lane & 15;

  __shared__ __align__(16) float    xi_s[DD];
  __shared__ __align__(16) _Float16 Af[16384];   // 32 KB: [ksl 0..7][jg][q][cc][e]
  __shared__ float pre_s[HH];       // S_i + b1
  __shared__ float pre2_s[HH];      // T_i + b1 (mirror)
  __shared__ float w2_s[HH];
  __shared__ float sc_s[4][64];

  xi_s[t]   = X[(size_t)bi * DD + t];
  pre_s[t]  = S[(size_t)bi * HH + t] + b1[t];
  pre2_s[t] = T[(size_t)bi * HH + t] + b1[t];
  w2_s[t]   = W2[t];

  const float* __restrict__ Tb = T + (size_t)b * NN * HH;
  const float* __restrict__ Sb = S + (size_t)b * NN * HH;

  const int jloc = t & 63;
  const int jg   = jloc >> 4;
  const int ccw  = jloc & 15;
  const float* __restrict__ xjrow = X + (size_t)(b * NN + jbase + jloc) * DD;

  const char* __restrict__ bsrc = (const char*)Wst + hg * 4096 + (size_t)lane * 16;

  floatx4 a00 = (floatx4)0.f, a01 = (floatx4)0.f, a02 = (floatx4)0.f, a03 = (floatx4)0.f;
  floatx4 a10 = (floatx4)0.f, a11 = (floatx4)0.f, a12 = (floatx4)0.f, a13 = (floatx4)0.f;
  floatx4 a20 = (floatx4)0.f, a21 = (floatx4)0.f, a22 = (floatx4)0.f, a23 = (floatx4)0.f;
  floatx4 a30 = (floatx4)0.f, a31 = (floatx4)0.f, a32 = (floatx4)0.f, a33 = (floatx4)0.f;

#pragma unroll 1
  for (int half = 0; half < 2; ++half) {
    __syncthreads();                 // header ready / prior Af reads done

#pragma unroll
    for (int idx = 0; idx < 8; ++idx) {
      const int ksq = (t >> 6) * 8 + idx;       // local 0..31
      const int d0  = (half * 32 + ksq) * 4;
      const int ksl = ksq >> 2;
      const int qw  = ksq & 3;
      const float4 xi4 = *(const float4*)&xi_s[d0];
      const float4 xj4 = *(const float4*)(xjrow + d0);
      *(half8*)&Af[(ksl * 16 + jg * 4 + qw) * 128 + ccw * 8] = make_afrag(xi4, xj4);
    }
    __syncthreads();                 // Af ready; K-loop below is barrier-free

    const char* bk0 = bsrc + (half * 8) * 16384;
    half8 nb0 = *(const half8*)(bk0);
    half8 nb1 = *(const half8*)(bk0 + 1024);
    half8 nb2 = *(const half8*)(bk0 + 2048);
    half8 nb3 = *(const half8*)(bk0 + 3072);
    const _Float16* ap0 = &Af[lane * 8];
    half8 na0 = *(const half8*)(ap0);
    half8 na1 = *(const half8*)(ap0 + 512);
    half8 na2 = *(const half8*)(ap0 + 1024);
    half8 na3 = *(const half8*)(ap0 + 1536);

#pragma unroll
    for (int ksl = 0; ksl < 8; ++ksl) {
      const half8 cb0 = nb0, cb1 = nb1, cb2 = nb2, cb3 = nb3;
      const half8 ca0 = na0, ca1 = na1, ca2 = na2, ca3 = na3;
      if (ksl < 7) {
        const char* bk = bsrc + (half * 8 + ksl + 1) * 16384;
        nb0 = *(const half8*)(bk);
        nb1 = *(const half8*)(bk + 1024);
        nb2 = *(const half8*)(bk + 2048);
        nb3 = *(const half8*)(bk + 3072);
        const _Float16* ap = &Af[(ksl + 1) * 2048 + lane * 8];
        na0 = *(const half8*)(ap);
        na1 = *(const half8*)(ap + 512);
        na2 = *(const half8*)(ap + 1024);
        na3 = *(const half8*)(ap + 1536);
      }
      MFMA16(ca0, cb0, a00); MFMA16(ca0, cb1, a01); MFMA16(ca0, cb2, a02); MFMA16(ca0, cb3, a03);
      MFMA16(ca1, cb0, a10); MFMA16(ca1, cb1, a11); MFMA16(ca1, cb2, a12); MFMA16(ca1, cb3, a13);
      MFMA16(ca2, cb0, a20); MFMA16(ca2, cb1, a21); MFMA16(ca2, cb2, a22); MFMA16(ca2, cb3, a23);
      MFMA16(ca3, cb0, a30); MFMA16(ca3, cb1, a31); MFMA16(ca3, cb2, a32); MFMA16(ca3, cb3, a33);
    }
  }

  // ---- direct epilogue: H = C + (S_i+b1) + T_j ; silu ; dot w2 ----
  float p00, p01, p02, p03, p10, p11, p12, p13;
  float p20, p21, p22, p23, p30, p31, p32, p33;
  p00=p01=p02=p03=p10=p11=p12=p13=0.f;
  p20=p21=p22=p23=p30=p31=p32=p33=0.f;

#define SILU_DOT(A, r, VROW, PREV, P) { \
    const float tv = VROW[(size_t)(jbase + jj16 + q * 4 + r) * HH + h]; \
    const float hv = A[r] + PREV + tv; \
    const float sv = hv * __builtin_amdgcn_rcpf(1.f + __expf(-hv)); \
    P = fmaf(sv, w2v, P); }

#define EPI_HH(hh, A0, A1, A2, A3, VROW, PRE) { \
    const int h = hg * 64 + hh * 16 + cc; \
    const float w2v = w2_s[h]; \
    const float pv  = PRE[h]; \
    { const int jj16 = 0;  SILU_DOT(A0, 0, VROW, pv, p00) SILU_DOT(A0, 1, VROW, pv, p01) \
                           SILU_DOT(A0, 2, VROW, pv, p02) SILU_DOT(A0, 3, VROW, pv, p03) } \
    { const int jj16 = 16; SILU_DOT(A1, 0, VROW, pv, p10) SILU_DOT(A1, 1, VROW, pv, p11) \
                           SILU_DOT(A1, 2, VROW, pv, p12) SILU_DOT(A1, 3, VROW, pv, p13) } \
    { const int jj16 = 32; SILU_DOT(A2, 0, VROW, pv, p20) SILU_DOT(A2, 1, VROW, pv, p21) \
                           SILU_DOT(A2, 2, VROW, pv, p22) SILU_DOT(A2, 3, VROW, pv, p23) } \
    { const int jj16 = 48; SILU_DOT(A3, 0, VROW, pv, p30) SILU_DOT(A3, 1, VROW, pv, p31) \
                           SILU_DOT(A3, 2, VROW, pv, p32) SILU_DOT(A3, 3, VROW, pv, p33) } }

#define REDW(P, jj, r) { \
    float v = P; \
    v += __shfl_xor(v, 1); v += __shfl_xor(v, 2); \
    v += __shfl_xor(v, 4); v += __shfl_xor(v, 8); \
    if (cc == 0) sc_s[hg][jj * 16 + q * 4 + r] = v; }

#define REDW_ALL \
  REDW(p00, 0, 0) REDW(p01, 0, 1) REDW(p02, 0, 2) REDW(p03, 0, 3) \
  REDW(p10, 1, 0) REDW(p11, 1, 1) REDW(p12, 1, 2) REDW(p13, 1, 3) \
  REDW(p20, 2, 0) REDW(p21, 2, 1) REDW(p22, 2, 2) REDW(p23, 2, 3) \
  REDW(p30, 3, 0) REDW(p31, 3, 1) REDW(p32, 3, 2) REDW(p33, 3, 3)

  EPI_HH(0, a00, a10, a20, a30, Tb, pre_s)
  EPI_HH(1, a01, a11, a21, a31, Tb, pre_s)
  EPI_HH(2, a02, a12, a22, a32, Tb, pre_s)
  EPI_HH(3, a03, a13, a23, a33, Tb, pre_s)
  REDW_ALL
  __syncthreads();

  if (t < 64) {
    float s = sc_s[0][t] + sc_s[1][t] + sc_s[2][t] + sc_s[3][t] + b2[0];
    const int jg2 = jbase + t;
    if (jg2 == i) s = NEGV;
    Sc[(size_t)bi * NN + jg2] = s;
  }

  // ---- mirror epilogue (pure-upper blocks): H' = C + S_j + (T_i+b1) ----
  if (isUp) {
    __syncthreads();                 // sc_s reads done before overwrite
    p00=p01=p02=p03=p10=p11=p12=p13=0.f;
    p20=p21=p22=p23=p30=p31=p32=p33=0.f;
    EPI_HH(0, a00, a10, a20, a30, Sb, pre2_s)
    EPI_HH(1, a01, a11, a21, a31, Sb, pre2_s)
    EPI_HH(2, a02, a12, a22, a32, Sb, pre2_s)
    EPI_HH(3, a03, a13, a23, a33, Sb, pre2_s)
    REDW_ALL
    __syncthreads();
    if (t < 64) {
      const float s = sc_s[0][t] + sc_s[1][t] + sc_s[2][t] + sc_s[3][t] + b2[0];
      Sc[(size_t)(b * NN + jbase + t) * NN + i] = s;   // Sc[j, i]
    }
  }
}

// ---------------- softmax over j, one block per (b,i) --------------------------
__global__ __launch_bounds__(256) void softmax_kernel(const float* __restrict__ Sc,
                                                      float* __restrict__ out) {
  const int bi = blockIdx.x;
  const int t  = threadIdx.x;
  __shared__ float red[NN];
  const float s = Sc[(size_t)bi * NN + t];
  red[t] = s;
  __syncthreads();
  for (int k = 128; k > 0; k >>= 1) {
    if (t < k) red[t] = fmaxf(red[t], red[t + k]);
    __syncthreads();
  }
  const float m = red[0];
  __syncthreads();
  const float e = __expf(s - m);
  red[t] = e;
  __syncthreads();
  for (int k = 128; k > 0; k >>= 1) {
    if (t < k) red[t] += red[t + k];
    __syncthreads();
  }
  out[(size_t)bi * NN + t] = e / red[0];
}

extern "C" void kernel_launch(void* const* d_in, const int* in_sizes, int n_in,
                              void* d_out, int out_size, void* d_ws, size_t ws_size,
                              hipStream_t stream) {
  const float* X  = (const float*)d_in[0];
  const float* W1 = (const float*)d_in[1];
  const float* b1 = (const float*)d_in[2];
  const float* W2 = (const float*)d_in[3];
  const float* b2 = (const float*)d_in[4];
  float* out = (float*)d_out;

  float*     Sws = (float*)d_ws;                             // 1 MB
  float*     Tws = Sws + (size_t)BB * NN * HH;               // 1 MB
  _Float16*  Wst = (_Float16*)(Tws + (size_t)BB * NN * HH);  // 256 KB
  float*     Scw = (float*)(Wst + (size_t)16 * HH * 32);     // 1 MB

  wconv_kernel<<<256, 256, 0, stream>>>(W1, Wst);
  prep_st<<<128, 256, 0, stream>>>(X, W1, Sws, Tws);
  score_mfma<<<dim3(640, BB), 256, 0, stream>>>(X, b1, W2, b2, Sws, Tws, Wst, Scw);
  softmax_kernel<<<BB * NN, 256, 0, stream>>>(Scw, out);
}

// Round 20
// 172.892 us; speedup vs baseline: 1.0678x; 1.0678x over previous
//
#include <hip/hip_runtime.h>

#define BB 4
#define NN 256
#define DD 256
#define HH 256
#define NEGV -1.0e9f

typedef _Float16 half8 __attribute__((ext_vector_type(8)));
typedef __fp16   fp16x2 __attribute__((ext_vector_type(2)));
typedef float floatx4 __attribute__((ext_vector_type(4)));

// ---------------- prep (split-K): S/T partial projections + wconv --------------
// Grid (512, 2): block (g, kk) -> rows 2g..2g+1, d in [kk*128, kk*128+128).
// Serial FMA chain halves vs R18 (prep is latency-bound, not traffic-bound:
// R19's 128-block RPB=8 version left half the CUs idle and regressed).
// Partials atomicAdd into memset-zeroed S/T: exactly 2 addends -> deterministic.
// Wst layout (R13 map): [ks][hgrp][q][cc][e] halves; converted when kk==0,g<256.
__global__ __launch_bounds__(256) void prep_split(const float* __restrict__ X,
                                                  const float* __restrict__ W1,
                                                  float* __restrict__ S,
                                                  float* __restrict__ T,
                                                  _Float16* __restrict__ Wst) {
  const int g  = blockIdx.x;   // 0..511
  const int kk = blockIdx.y;   // 0..1
  const int h  = threadIdx.x;  // 0..255

  if (kk == 0 && g < 256) {    // weight conversion for d = g
    const float wcv = W1[(size_t)(2 * DD + g) * HH + h];
    const float wdv = W1[(size_t)(3 * DD + g) * HH + h];
    const int ks = g >> 4;
    const int dd = g & 15;
    const int q  = dd >> 2;
    const int e  = (dd & 3) * 2;
    const int hgrp = h >> 4;
    const int ccw  = h & 15;
    _Float16* p = Wst + ((size_t)((ks * 16 + hgrp) * 4 + q) * 16 + ccw) * 8 + e;
    p[0] = (_Float16)wcv;
    p[1] = (_Float16)wdv;
  }

  const int row0 = g * 2;
  const int dbase = kk * 128;
  __shared__ float xr[2][128];
  if (h < 128) xr[0][h] = X[(size_t)row0 * DD + dbase + h];
  else         xr[1][h - 128] = X[(size_t)(row0 + 1) * DD + dbase + (h - 128)];
  __syncthreads();

  const float* __restrict__ Wa = W1 + (size_t)dbase * HH;
  const float* __restrict__ Wb = W1 + (size_t)(DD + dbase) * HH;
  float sa0 = 0.f, sa1 = 0.f, sb0 = 0.f, sb1 = 0.f;
#pragma unroll 8
  for (int d = 0; d < 128; ++d) {
    const float wa = Wa[(size_t)d * HH + h];
    const float wb = Wb[(size_t)d * HH + h];
    sa0 = fmaf(xr[0][d], wa, sa0);  sb0 = fmaf(xr[0][d], wb, sb0);
    sa1 = fmaf(xr[1][d], wa, sa1);  sb1 = fmaf(xr[1][d], wb, sb1);
  }
  atomicAdd(&S[(size_t)(row0 + 0) * HH + h], sa0);
  atomicAdd(&T[(size_t)(row0 + 0) * HH + h], sb0);
  atomicAdd(&S[(size_t)(row0 + 1) * HH + h], sa1);
  atomicAdd(&T[(size_t)(row0 + 1) * HH + h], sb1);
}

__device__ __forceinline__ half8 make_afrag(const float4 xi, const float4 xj) {
  fp16x2 p0 = __builtin_amdgcn_cvt_pkrtz(__builtin_fabsf(xi.x - xj.x), xi.x * xj.x);
  fp16x2 p1 = __builtin_amdgcn_cvt_pkrtz(__builtin_fabsf(xi.y - xj.y), xi.y * xj.y);
  fp16x2 p2 = __builtin_amdgcn_cvt_pkrtz(__builtin_fabsf(xi.z - xj.z), xi.z * xj.z);
  fp16x2 p3 = __builtin_amdgcn_cvt_pkrtz(__builtin_fabsf(xi.w - xj.w), xi.w * xj.w);
  uint4 u;
  u.x = __builtin_bit_cast(unsigned int, p0);
  u.y = __builtin_bit_cast(unsigned int, p1);
  u.z = __builtin_bit_cast(unsigned int, p2);
  u.w = __builtin_bit_cast(unsigned int, p3);
  return __builtin_bit_cast(half8, u);
}

#define MFMA16(af, bf, acc) acc = __builtin_amdgcn_mfma_f32_16x16x32_f16(af, bf, acc, 0, 0, 0)

// ---------------- score: SYMMETRY-PRUNED pair tiles (R18, unchanged) -----------
__global__ __launch_bounds__(256, 2) void score_mfma(
    const float* __restrict__ X,  const float* __restrict__ b1,
    const float* __restrict__ W2, const float* __restrict__ b2,
    const float* __restrict__ S,  const float* __restrict__ T,
    const _Float16* __restrict__ Wst, float* __restrict__ Sc) {

  const int beta = blockIdx.x;      // 0..639
  const int b    = blockIdx.y;
  int i, qt;
  if (beta < 256)      { i = beta >> 2;                    qt = beta & 3; }
  else if (beta < 448) { const int g = beta - 256; const int d3 = g / 3;
                         i = 64 + d3;                      qt = 1 + (g - 3 * d3); }
  else if (beta < 576) { const int g = beta - 448;
                         i = 128 + (g >> 1);               qt = 2 + (g & 1); }
  else                 { i = 192 + (beta - 576);           qt = 3; }
  const int bi    = b * NN + i;
  const int jbase = qt * 64;
  const int isUp  = qt > (i >> 6);  // block-uniform

  const int t     = threadIdx.x;
  const int lane  = t & 63;
  const int hg    = t >> 6;         // 0..3
  const int q     = lane >> 4;
  const int cc    = lane & 15;

  __shared__ __align__(16) float    xi_s[DD];
  __shared__ __align__(16) _Float16 Af[16384];   // 32 KB: [ksl 0..7][jg][q][cc][e]
  __shared__ float pre_s[HH];       // S_i + b1
  __shared__ float pre2_s[HH];      // T_i + b1 (mirror)
  __shared__ float w2_s[HH];
  __shared__ float sc_s[4][64];

  xi_s[t]   = X[(size_t)bi * DD + t];
  pre_s[t]  = S[(size_t)bi * HH + t] + b1[t];
  pre2_s[t] = T[(size_t)bi * HH + t] + b1[t];
  w2_s[t]   = W2[t];

  const float* __restrict__ Tb = T + (size_t)b * NN * HH;
  const float* __restrict__ Sb = S + (size_t)b * NN * HH;

  const int jloc = t & 63;
  const int jg   = jloc >> 4;
  const int ccw  = jloc & 15;
  const float* __restrict__ xjrow = X + (size_t)(b * NN + jbase + jloc) * DD;

  const char* __restrict__ bsrc = (const char*)Wst + hg * 4096 + (size_t)lane * 16;

  floatx4 a00 = (floatx4)0.f, a01 = (floatx4)0.f, a02 = (floatx4)0.f, a03 = (floatx4)0.f;
  floatx4 a10 = (floatx4)0.f, a11 = (floatx4)0.f, a12 = (floatx4)0.f, a13 = (floatx4)0.f;
  floatx4 a20 = (floatx4)0.f, a21 = (floatx4)0.f, a22 = (floatx4)0.f, a23 = (floatx4)0.f;
  floatx4 a30 = (floatx4)0.f, a31 = (floatx4)0.f, a32 = (floatx4)0.f, a33 = (floatx4)0.f;

#pragma unroll 1
  for (int half = 0; half < 2; ++half) {
    __syncthreads();                 // header ready / prior Af reads done

#pragma unroll
    for (int idx = 0; idx < 8; ++idx) {
      const int ksq = (t >> 6) * 8 + idx;       // local 0..31
      const int d0  = (half * 32 + ksq) * 4;
      const int ksl = ksq >> 2;
      const int qw  = ksq & 3;
      const float4 xi4 = *(const float4*)&xi_s[d0];
      const float4 xj4 = *(const float4*)(xjrow + d0);
      *(half8*)&Af[(ksl * 16 + jg * 4 + qw) * 128 + ccw * 8] = make_afrag(xi4, xj4);
    }
    __syncthreads();                 // Af ready; K-loop below is barrier-free

    const char* bk0 = bsrc + (half * 8) * 16384;
    half8 nb0 = *(const half8*)(bk0);
    half8 nb1 = *(const half8*)(bk0 + 1024);
    half8 nb2 = *(const half8*)(bk0 + 2048);
    half8 nb3 = *(const half8*)(bk0 + 3072);
    const _Float16* ap0 = &Af[lane * 8];
    half8 na0 = *(const half8*)(ap0);
    half8 na1 = *(const half8*)(ap0 + 512);
    half8 na2 = *(const half8*)(ap0 + 1024);
    half8 na3 = *(const half8*)(ap0 + 1536);

#pragma unroll
    for (int ksl = 0; ksl < 8; ++ksl) {
      const half8 cb0 = nb0, cb1 = nb1, cb2 = nb2, cb3 = nb3;
      const half8 ca0 = na0, ca1 = na1, ca2 = na2, ca3 = na3;
      if (ksl < 7) {
        const char* bk = bsrc + (half * 8 + ksl + 1) * 16384;
        nb0 = *(const half8*)(bk);
        nb1 = *(const half8*)(bk + 1024);
        nb2 = *(const half8*)(bk + 2048);
        nb3 = *(const half8*)(bk + 3072);
        const _Float16* ap = &Af[(ksl + 1) * 2048 + lane * 8];
        na0 = *(const half8*)(ap);
        na1 = *(const half8*)(ap + 512);
        na2 = *(const half8*)(ap + 1024);
        na3 = *(const half8*)(ap + 1536);
      }
      MFMA16(ca0, cb0, a00); MFMA16(ca0, cb1, a01); MFMA16(ca0, cb2, a02); MFMA16(ca0, cb3, a03);
      MFMA16(ca1, cb0, a10); MFMA16(ca1, cb1, a11); MFMA16(ca1, cb2, a12); MFMA16(ca1, cb3, a13);
      MFMA16(ca2, cb0, a20); MFMA16(ca2, cb1, a21); MFMA16(ca2, cb2, a22); MFMA16(ca2, cb3, a23);
      MFMA16(ca3, cb0, a30); MFMA16(ca3, cb1, a31); MFMA16(ca3, cb2, a32); MFMA16(ca3, cb3, a33);
    }
  }

  // ---- direct epilogue: H = C + (S_i+b1) + T_j ; silu ; dot w2 ----
  float p00, p01, p02, p03, p10, p11, p12, p13;
  float p20, p21, p22, p23, p30, p31, p32, p33;
  p00=p01=p02=p03=p10=p11=p12=p13=0.f;
  p20=p21=p22=p23=p30=p31=p32=p33=0.f;

#define SILU_DOT(A, r, VROW, PREV, P) { \
    const float tv = VROW[(size_t)(jbase + jj16 + q * 4 + r) * HH + h]; \
    const float hv = A[r] + PREV + tv; \
    const float sv = hv * __builtin_amdgcn_rcpf(1.f + __expf(-hv)); \
    P = fmaf(sv, w2v, P); }

#define EPI_HH(hh, A0, A1, A2, A3, VROW, PRE) { \
    const int h = hg * 64 + hh * 16 + cc; \
    const float w2v = w2_s[h]; \
    const float pv  = PRE[h]; \
    { const int jj16 = 0;  SILU_DOT(A0, 0, VROW, pv, p00) SILU_DOT(A0, 1, VROW, pv, p01) \
                           SILU_DOT(A0, 2, VROW, pv, p02) SILU_DOT(A0, 3, VROW, pv, p03) } \
    { const int jj16 = 16; SILU_DOT(A1, 0, VROW, pv, p10) SILU_DOT(A1, 1, VROW, pv, p11) \
                           SILU_DOT(A1, 2, VROW, pv, p12) SILU_DOT(A1, 3, VROW, pv, p13) } \
    { const int jj16 = 32; SILU_DOT(A2, 0, VROW, pv, p20) SILU_DOT(A2, 1, VROW, pv, p21) \
                           SILU_DOT(A2, 2, VROW, pv, p22) SILU_DOT(A2, 3, VROW, pv, p23) } \
    { const int jj16 = 48; SILU_DOT(A3, 0, VROW, pv, p30) SILU_DOT(A3, 1, VROW, pv, p31) \
                           SILU_DOT(A3, 2, VROW, pv, p32) SILU_DOT(A3, 3, VROW, pv, p33) } }

#define REDW(P, jj, r) { \
    float v = P; \
    v += __shfl_xor(v, 1); v += __shfl_xor(v, 2); \
    v += __shfl_xor(v, 4); v += __shfl_xor(v, 8); \
    if (cc == 0) sc_s[hg][jj * 16 + q * 4 + r] = v; }

#define REDW_ALL \
  REDW(p00, 0, 0) REDW(p01, 0, 1) REDW(p02, 0, 2) REDW(p03, 0, 3) \
  REDW(p10, 1, 0) REDW(p11, 1, 1) REDW(p12, 1, 2) REDW(p13, 1, 3) \
  REDW(p20, 2, 0) REDW(p21, 2, 1) REDW(p22, 2, 2) REDW(p23, 2, 3) \
  REDW(p30, 3, 0) REDW(p31, 3, 1) REDW(p32, 3, 2) REDW(p33, 3, 3)

  EPI_HH(0, a00, a10, a20, a30, Tb, pre_s)
  EPI_HH(1, a01, a11, a21, a31, Tb, pre_s)
  EPI_HH(2, a02, a12, a22, a32, Tb, pre_s)
  EPI_HH(3, a03, a13, a23, a33, Tb, pre_s)
  REDW_ALL
  __syncthreads();

  if (t < 64) {
    float s = sc_s[0][t] + sc_s[1][t] + sc_s[2][t] + sc_s[3][t] + b2[0];
    const int jg2 = jbase + t;
    if (jg2 == i) s = NEGV;
    Sc[(size_t)bi * NN + jg2] = s;
  }

  // ---- mirror epilogue (pure-upper blocks): H' = C + S_j + (T_i+b1) ----
  if (isUp) {
    __syncthreads();                 // sc_s reads done before overwrite
    p00=p01=p02=p03=p10=p11=p12=p13=0.f;
    p20=p21=p22=p23=p30=p31=p32=p33=0.f;
    EPI_HH(0, a00, a10, a20, a30, Sb, pre2_s)
    EPI_HH(1, a01, a11, a21, a31, Sb, pre2_s)
    EPI_HH(2, a02, a12, a22, a32, Sb, pre2_s)
    EPI_HH(3, a03, a13, a23, a33, Sb, pre2_s)
    REDW_ALL
    __syncthreads();
    if (t < 64) {
      const float s = sc_s[0][t] + sc_s[1][t] + sc_s[2][t] + sc_s[3][t] + b2[0];
      Sc[(size_t)(b * NN + jbase + t) * NN + i] = s;   // Sc[j, i]
    }
  }
}

// ---------------- softmax over j, one block per (b,i) --------------------------
__global__ __launch_bounds__(256) void softmax_kernel(const float* __restrict__ Sc,
                                                      float* __restrict__ out) {
  const int bi = blockIdx.x;
  const int t  = threadIdx.x;
  __shared__ float red[NN];
  const float s = Sc[(size_t)bi * NN + t];
  red[t] = s;
  __syncthreads();
  for (int k = 128; k > 0; k >>= 1) {
    if (t < k) red[t] = fmaxf(red[t], red[t + k]);
    __syncthreads();
  }
  const float m = red[0];
  __syncthreads();
  const float e = __expf(s - m);
  red[t] = e;
  __syncthreads();
  for (int k = 128; k > 0; k >>= 1) {
    if (t < k) red[t] += red[t + k];
    __syncthreads();
  }
  out[(size_t)bi * NN + t] = e / red[0];
}

extern "C" void kernel_launch(void* const* d_in, const int* in_sizes, int n_in,
                              void* d_out, int out_size, void* d_ws, size_t ws_size,
                              hipStream_t stream) {
  const float* X  = (const float*)d_in[0];
  const float* W1 = (const float*)d_in[1];
  const float* b1 = (const float*)d_in[2];
  const float* W2 = (const float*)d_in[3];
  const float* b2 = (const float*)d_in[4];
  float* out = (float*)d_out;

  float*     Sws = (float*)d_ws;                             // 1 MB
  float*     Tws = Sws + (size_t)BB * NN * HH;               // 1 MB
  _Float16*  Wst = (_Float16*)(Tws + (size_t)BB * NN * HH);  // 256 KB
  float*     Scw = (float*)(Wst + (size_t)16 * HH * 32);     // 1 MB

  // zero S/T for split-K atomic accumulation (stream op — graph-capture safe)
  hipMemsetAsync(Sws, 0, (size_t)2 * BB * NN * HH * sizeof(float), stream);

  prep_split<<<dim3(512, 2), 256, 0, stream>>>(X, W1, Sws, Tws, Wst);
  score_mfma<<<dim3(640, BB), 256, 0, stream>>>(X, b1, W2, b2, Sws, Tws, Wst, Scw);
  softmax_kernel<<<BB * NN, 256, 0, stream>>>(Scw, out);
}